// Round 5
// baseline (215.040 us; speedup 1.0000x reference)
//
#include <hip/hip_runtime.h>
#include <math.h>

// Problem constants
#define NB 16
#define NL 128
#define DIN 512
#define NH 256
#define NTAGS 45
#define NM (NB*NL)          // 2048 rows
#define NJ (NL+1)           // 129 arc columns

// ws layout (floats)
#define H_OFF     0                        // 4 slabs of NM*NH (g1 K-split partials)
#define U_OFF     (4*NM*NH)                // 2 slabs of NM*NH (u partials)
#define HV_OFF    (6*NM*NH)                // 2 slabs of NM*NH (hv partials)
#define VROOT_OFF (8*NM*NH)                // NH
#define ACC_OFF   (VROOT_OFF + NH)         // [0]=unused, [1]=done counter (int)
#define PM_OFF    (ACC_OFF + 4)            // 2 x NM arc-softmax partial max
#define PE_OFF    (PM_OFF + 2*NM)          // 2 x NM arc-softmax partial sum
#define SA_OFF    (PE_OFF + 2*NM)          // NM selected-arc score
#define LCE_OFF   (SA_OFF + NM)            // NM label CE

// ---------------------------------------------------------------------------
// Kernel 1: hidden partials, K-split x4. h_z = C[:, z*128:+128] @ W1[z*128:+128,:]
// 64x64 tile, 4x4/thread, BK=32 (4 sync pairs/block, was 8). grid (32,4,4)=512.
// bias+relu deferred to K2's A-stage. Block (0,0,0) zeroes the done counter.
// ---------------------------------------------------------------------------
__global__ __launch_bounds__(256) void gemm_hidden(
    const float* __restrict__ A,   // 2048 x 512
    const float* __restrict__ W,   // 512 x 256
    float* __restrict__ h,         // 4 x 2048 x 256 partials
    float* __restrict__ accum)
{
    __shared__ float As[32][68];   // [k][m]
    __shared__ float Bs[32][68];   // [k][n]
    int m0 = blockIdx.x * 64;
    int n0 = blockIdx.y * 64;
    int kbase = blockIdx.z * 128;
    int tid = threadIdx.x;
    if (blockIdx.x == 0 && blockIdx.y == 0 && blockIdx.z == 0 && tid == 0) {
        accum[0] = 0.f;
        ((int*)accum)[1] = 0;
    }
    int tm = tid >> 4, tn = tid & 15;
    float acc[4][4] = {{0.f}};

    for (int k0 = kbase; k0 < kbase + 128; k0 += 32) {
        #pragma unroll
        for (int s = 0; s < 2; s++) {
            int idx = tid + s * 256;               // 0..511
            int arow = idx >> 3, akq = (idx & 7) * 4;
            float4 a4 = *(const float4*)&A[(size_t)(m0 + arow) * DIN + k0 + akq];
            As[akq + 0][arow] = a4.x; As[akq + 1][arow] = a4.y;
            As[akq + 2][arow] = a4.z; As[akq + 3][arow] = a4.w;
            int bk = idx >> 4, bn = (idx & 15) * 4;
            *(float4*)&Bs[bk][bn] =
                *(const float4*)&W[(size_t)(k0 + bk) * NH + n0 + bn];
        }
        __syncthreads();
        #pragma unroll
        for (int kk = 0; kk < 32; kk++) {
            float4 av = *(const float4*)&As[kk][tm * 4];
            float4 bv = *(const float4*)&Bs[kk][tn * 4];
            float ar[4] = {av.x, av.y, av.z, av.w};
            float br[4] = {bv.x, bv.y, bv.z, bv.w};
            #pragma unroll
            for (int r = 0; r < 4; r++)
                #pragma unroll
                for (int c = 0; c < 4; c++)
                    acc[r][c] = fmaf(ar[r], br[c], acc[r][c]);
        }
        __syncthreads();
    }
    float* hz = h + (size_t)blockIdx.z * NM * NH;
    int col = n0 + tn * 4;
    #pragma unroll
    for (int r = 0; r < 4; r++) {
        int row = m0 + tm * 4 + r;
        *(float4*)&hz[(size_t)row * NH + col] =
            make_float4(acc[r][0], acc[r][1], acc[r][2], acc[r][3]);
    }
}

// ---------------------------------------------------------------------------
// Kernel 2: u = hidden@Wa ; hv = hidden@Wb ; vroot = root@Wb
// hidden reconstructed on the fly: relu(h0+h1+h2+h3+b1) during A-stage.
// 64x64 tile, 4x4/thread, BK=32, K-split x2 -> partials u0/u1, hv0/hv1.
// grid (33,8,2); x==32,z==0,y>=4 computes vroot (full K).
// ---------------------------------------------------------------------------
__global__ __launch_bounds__(256) void gemm_uv(
    const float* __restrict__ h,      // 4 x 2048 x 256 partials
    const float* __restrict__ b1,     // 256 (hidden bias)
    const float* __restrict__ Wp,     // 512 x 256
    const float* __restrict__ root,   // 256
    float* __restrict__ uu,           // 2 x 2048 x 256 partials
    float* __restrict__ hvv,          // 2 x 2048 x 256 partials
    float* __restrict__ vroot)        // 256
{
    __shared__ float As[32][68];
    __shared__ float Bs[32][68];
    __shared__ float part[4][64];
    int n0 = blockIdx.y * 64;
    int tid = threadIdx.x;

    if (blockIdx.x == 32) {            // root row blocks
        if (blockIdx.z != 0 || n0 < NH) return;
        int col = (n0 - NH) + (tid & 63);
        int kc = tid >> 6;
        float p = 0.f;
        #pragma unroll 8
        for (int c = kc * 64; c < kc * 64 + 64; c++)
            p += root[c] * Wp[(size_t)(NH + c) * NH + col];
        part[kc][tid & 63] = p;
        __syncthreads();
        if (tid < 64)
            vroot[(n0 - NH) + tid] = part[0][tid] + part[1][tid]
                                   + part[2][tid] + part[3][tid];
        return;
    }

    int m0 = blockIdx.x * 64;
    int kbase = blockIdx.z * 128;
    bool isU = (n0 < NH);
    int tm = tid >> 4, tn = tid & 15;
    float acc[4][4] = {{0.f}};

    for (int k0 = kbase; k0 < kbase + 128; k0 += 32) {
        #pragma unroll
        for (int s = 0; s < 2; s++) {
            int idx = tid + s * 256;
            int arow = idx >> 3, akq = (idx & 7) * 4;
            size_t base = (size_t)(m0 + arow) * NH + k0 + akq;
            float4 p0 = *(const float4*)&h[base];
            float4 p1 = *(const float4*)&h[base + (size_t)1 * NM * NH];
            float4 p2 = *(const float4*)&h[base + (size_t)2 * NM * NH];
            float4 p3 = *(const float4*)&h[base + (size_t)3 * NM * NH];
            float4 bv = *(const float4*)&b1[k0 + akq];
            As[akq + 0][arow] = fmaxf(p0.x + p1.x + p2.x + p3.x + bv.x, 0.f);
            As[akq + 1][arow] = fmaxf(p0.y + p1.y + p2.y + p3.y + bv.y, 0.f);
            As[akq + 2][arow] = fmaxf(p0.z + p1.z + p2.z + p3.z + bv.z, 0.f);
            As[akq + 3][arow] = fmaxf(p0.w + p1.w + p2.w + p3.w + bv.w, 0.f);
            int bk = idx >> 4, bn = (idx & 15) * 4;
            int c = k0 + bk;
            float4 b4;
            if (isU) b4 = *(const float4*)&Wp[(size_t)c * NH + n0 + bn];
            else     b4 = *(const float4*)&Wp[(size_t)(NH + c) * NH + (n0 - NH) + bn];
            *(float4*)&Bs[bk][bn] = b4;
        }
        __syncthreads();
        #pragma unroll
        for (int kk = 0; kk < 32; kk++) {
            float4 av = *(const float4*)&As[kk][tm * 4];
            float4 bv2 = *(const float4*)&Bs[kk][tn * 4];
            float ar[4] = {av.x, av.y, av.z, av.w};
            float br[4] = {bv2.x, bv2.y, bv2.z, bv2.w};
            #pragma unroll
            for (int r = 0; r < 4; r++)
                #pragma unroll
                for (int cc = 0; cc < 4; cc++)
                    acc[r][cc] = fmaf(ar[r], br[cc], acc[r][cc]);
        }
        __syncthreads();
    }
    float* dst = (isU ? uu : hvv) + (size_t)blockIdx.z * NM * NH;
    int col = (isU ? n0 : n0 - NH) + tn * 4;
    #pragma unroll
    for (int r = 0; r < 4; r++) {
        int row = m0 + tm * 4 + r;
        *(float4*)&dst[(size_t)row * NH + col] =
            make_float4(acc[r][0], acc[r][1], acc[r][2], acc[r][3]);
    }
}

// ---------------------------------------------------------------------------
// Kernel 3: fused scores+loss, j-half split, wave-per-row LDS-broadcast path.
// Grid (NB, 32, 2) = 1024 blocks. Block = 4 waves = 4 rows x one j-half
// (h=0: j 0..63; h=1: j 64..128 incl. root-relative col 128).
// Per k-chunk (64 k): v staged k-major float2 [kk2][j_loc] (hv0+hv1 merged);
// wave's lane owns j = j0+lane (one acc reg). j=128 + sel on lanes<32
// k-slices (h / owner only). u staged once (u0+u1+bp merged) -> LDS
// broadcasts. Per (row,half): write (m,e) partials; owner half writes
// (s_arc, lab_ce). Done-counter tail merges via log-add-exp, finalizes.
// ---------------------------------------------------------------------------
#define NBLK (NB*32*2)   // 1024

__global__ __launch_bounds__(256) void score_loss_kernel(
    const float* __restrict__ uu, const float* __restrict__ hvv,
    const float* __restrict__ vroot, const float* __restrict__ W_arc,
    const float* __restrict__ bp,
    const float* __restrict__ W_lab, const float* __restrict__ b_lab,
    const int* __restrict__ slens, const int* __restrict__ arcs,
    const int* __restrict__ labels,
    float* __restrict__ pm, float* __restrict__ pe,
    float* __restrict__ sa, float* __restrict__ lce,
    float* __restrict__ accum, float* __restrict__ out)
{
    __shared__ float2 v2_s[32][66];    // [kk2][j_loc] 16,896 B
    __shared__ float2 u2_s[4][128];    // [row][kk2]    4,096 B
    __shared__ float2 wa2_s[128];      //               1,024 B
    __shared__ float2 sel2_s[32][5];   // [kk2][row]    1,280 B
    __shared__ float  rs_s[4];
    __shared__ int    arc_s[4], lab_s[4];
    __shared__ int    lastf;

    int bb = blockIdx.x;
    int i0 = blockIdx.y * 4;
    int h  = blockIdx.z;
    int tid = threadIdx.x;
    int w = tid >> 6;          // wave index = local row
    int lane = tid & 63;
    int slen = slens[bb];
    const int j0 = h ? 64 : 0;
    const int njh = 64 + h;    // staged cols (h=1 adds j=128 at col 64)

    if (i0 < slen) {
        // ---- one-time staging: u rows (u0+u1+bp), W_arc, arcs/labels ----
        {
            int r = tid >> 6, kq = (tid & 63) * 4;
            size_t base = (size_t)(bb * NL + i0 + r) * NH + kq;
            float4 a0 = *(const float4*)&uu[base];
            float4 a1 = *(const float4*)&uu[base + (size_t)NM * NH];
            float4 b4 = *(const float4*)&bp[kq];
            u2_s[r][(kq >> 1) + 0] = make_float2(a0.x + a1.x + b4.x,
                                                 a0.y + a1.y + b4.y);
            u2_s[r][(kq >> 1) + 1] = make_float2(a0.z + a1.z + b4.z,
                                                 a0.w + a1.w + b4.w);
        }
        if (tid < 128)
            wa2_s[tid] = *(const float2*)&W_arc[tid * 2];
        if (tid < 4) {
            int rg = bb * NL + i0 + tid;
            arc_s[tid] = arcs[rg];
            lab_s[tid] = labels[rg];
        }

        float acc = 0.f, s128 = 0.f, lacc = 0.f;

        for (int c = 0; c < 4; ++c) {
            int k0 = c * 64;
            // ---- stage v chunk k-major: njh cols x 64 k (hv0+hv1 merged) ----
            for (int idx = tid; idx < njh * 16; idx += 256) {
                int jl = idx >> 4, kq = (idx & 15) * 4;
                int jg = j0 + jl;
                float4 t4;
                if (jg == 0) {
                    t4 = *(const float4*)&vroot[k0 + kq];
                } else {
                    size_t base = (size_t)(bb * NL + jg - 1) * NH + k0 + kq;
                    float4 q0 = *(const float4*)&hvv[base];
                    float4 q1 = *(const float4*)&hvv[base + (size_t)NM * NH];
                    t4 = make_float4(q0.x + q1.x, q0.y + q1.y,
                                     q0.z + q1.z, q0.w + q1.w);
                }
                v2_s[(kq >> 1) + 0][jl] = make_float2(t4.x, t4.y);
                v2_s[(kq >> 1) + 1][jl] = make_float2(t4.z, t4.w);
            }
            __syncthreads();

            int a = arc_s[w];
            bool own = (a >= j0) && (a - j0 < njh);

            // ---- arc scores: lane owns j = j0 + lane ----
            const float2* urow = u2_s[w] + (k0 >> 1);
            const float2* warow = wa2_s + (k0 >> 1);
            #pragma unroll 8
            for (int kk2 = 0; kk2 < 32; ++kk2) {
                float2 u2 = urow[kk2];
                float2 w2 = warow[kk2];
                float2 va = v2_s[kk2][lane];
                acc += fmaxf(u2.x + va.x, 0.f) * w2.x
                     + fmaxf(u2.y + va.y, 0.f) * w2.y;
            }
            // ---- j=128 partial (h=1 only): lanes 0..31 own k-slices ----
            if (h && lane < 32) {
                float2 u2 = urow[lane];
                float2 w2 = warow[lane];
                float2 vv = v2_s[lane][64];
                s128 += fmaxf(u2.x + vv.x, 0.f) * w2.x
                      + fmaxf(u2.y + vv.y, 0.f) * w2.y;
            }
            // ---- sel staging + label logit partials (owner half only) ----
            if (own) {
                if (lane < 32) {
                    float2 u2 = urow[lane];
                    float2 vs = v2_s[lane][a - j0];
                    sel2_s[lane][w] = make_float2(fmaxf(u2.x + vs.x, 0.f),
                                                  fmaxf(u2.y + vs.y, 0.f));
                }
                if (lane < NTAGS) {
                    #pragma unroll 8
                    for (int kk2 = 0; kk2 < 32; ++kk2) {
                        float2 s2 = sel2_s[kk2][w];
                        float w0 = W_lab[(size_t)(k0 + 2 * kk2) * NTAGS + lane];
                        float w1 = W_lab[(size_t)(k0 + 2 * kk2 + 1) * NTAGS + lane];
                        lacc = fmaf(s2.x, w0, fmaf(s2.y, w1, lacc));
                    }
                }
            }
            __syncthreads();
        }

        // ---- per-row arc softmax partial (m, e) over this half ----
        float s128t = s128;
        #pragma unroll
        for (int off = 32; off > 0; off >>= 1)
            s128t += __shfl_xor(s128t, off);
        float m = acc;
        #pragma unroll
        for (int off = 32; off > 0; off >>= 1)
            m = fmaxf(m, __shfl_xor(m, off));
        if (h) m = fmaxf(m, s128t);
        float e = expf(acc - m);
        #pragma unroll
        for (int off = 32; off > 0; off >>= 1)
            e += __shfl_xor(e, off);
        if (h) e += expf(s128t - m);
        int row = bb * NL + i0 + w;
        if (lane == 0) {
            pm[h * NM + row] = m;
            pe[h * NM + row] = e;
        }

        // ---- owner half: selected-arc score + label CE ----
        int a = arc_s[w];
        if ((a >= j0) && (a - j0 < njh)) {
            float s_a = (a - j0 < 64) ? __shfl(acc, a - j0, 64) : s128t;
            float logit = (lane < NTAGS) ? (lacc + b_lab[lane]) : -INFINITY;
            float m2 = logit;
            #pragma unroll
            for (int off = 32; off > 0; off >>= 1)
                m2 = fmaxf(m2, __shfl_xor(m2, off));
            float e2 = (lane < NTAGS) ? expf(logit - m2) : 0.f;
            #pragma unroll
            for (int off = 32; off > 0; off >>= 1)
                e2 += __shfl_xor(e2, off);
            float lt = __shfl(logit, lab_s[w], 64);
            if (lane == 0) {
                sa[row] = s_a;
                lce[row] = (m2 + logf(e2)) - lt;
            }
        }
    }

    // ---- done counter; last block merges halves and finalizes ----
    __threadfence();
    __syncthreads();
    if (tid == 0)
        lastf = (atomicAdd((int*)accum + 1, 1) == NBLK - 1);
    __syncthreads();
    if (lastf) {
        __threadfence();
        float sum = 0.f;
        for (int r = tid; r < NM; r += 256) {
            int b = r >> 7, i = r & 127;
            if (i < slens[b]) {
                float m0 = pm[r], m1 = pm[NM + r];
                float e0 = pe[r], e1 = pe[NM + r];
                float M = fmaxf(m0, m1);
                float E = e0 * expf(m0 - M) + e1 * expf(m1 - M);
                sum += (M + logf(E)) - sa[r] + lce[r];
            }
        }
        #pragma unroll
        for (int off = 32; off > 0; off >>= 1)
            sum += __shfl_xor(sum, off);
        if (lane == 0) rs_s[tid >> 6] = sum;
        __syncthreads();
        if (tid == 0) {
            int d = 0;
            #pragma unroll
            for (int q = 0; q < NB; ++q) d += slens[q];
            out[0] = 0.5f * (rs_s[0] + rs_s[1] + rs_s[2] + rs_s[3])
                   / fmaxf((float)d, 1.f);
        }
    }
}

extern "C" void kernel_launch(void* const* d_in, const int* in_sizes, int n_in,
                              void* d_out, int out_size, void* d_ws, size_t ws_size,
                              hipStream_t stream) {
    (void)in_sizes; (void)n_in; (void)out_size; (void)ws_size;
    const float* ctx   = (const float*)d_in[0];
    const int*   slens = (const int*)  d_in[1];
    const int*   arcs  = (const int*)  d_in[2];
    const int*   labs  = (const int*)  d_in[3];
    const float* W1    = (const float*)d_in[4];
    const float* b1    = (const float*)d_in[5];
    const float* root  = (const float*)d_in[6];
    const float* Wp    = (const float*)d_in[7];
    const float* bp    = (const float*)d_in[8];
    const float* W_arc = (const float*)d_in[9];
    // d_in[10] = b_arc: constant shift, cancels in arc log-softmax CE
    const float* W_lab = (const float*)d_in[11];
    const float* b_lab = (const float*)d_in[12];
    float* out = (float*)d_out;

    float* ws    = (float*)d_ws;
    float* h     = ws + H_OFF;
    float* u     = ws + U_OFF;
    float* hv    = ws + HV_OFF;
    float* vroot = ws + VROOT_OFF;
    float* accum = ws + ACC_OFF;
    float* pm    = ws + PM_OFF;
    float* pe    = ws + PE_OFF;
    float* sal   = ws + SA_OFF;
    float* lcel  = ws + LCE_OFF;

    gemm_hidden<<<dim3(32, 4, 4), 256, 0, stream>>>(ctx, W1, h, accum);
    gemm_uv<<<dim3(33, 8, 2), 256, 0, stream>>>(h, b1, Wp, root, u, hv, vroot);
    score_loss_kernel<<<dim3(NB, 32, 2), 256, 0, stream>>>(
        u, hv, vroot, W_arc, bp, W_lab, b_lab, slens, arcs, labs,
        pm, pe, sal, lcel, accum, out);
}

// Round 7
// 139.670 us; speedup vs baseline: 1.5396x; 1.5396x over previous
//
#include <hip/hip_runtime.h>
#include <math.h>

// Problem constants
#define NB 16
#define NL 128
#define DIN 512
#define NH 256
#define NTAGS 45
#define NM (NB*NL)          // 2048 rows
#define NJ (NL+1)           // 129 arc columns

// ws layout (floats)
#define H_OFF     0                        // 2 slabs of NM*NH (k1 K-split partials)
#define U_OFF     (2*NM*NH)                // 1 slab  (u = hidden@Wa + bp)
#define HV_OFF    (3*NM*NH)                // 1 slab  (hv = hidden@Wb)
#define VROOT_OFF (4*NM*NH)                // NH
#define ACC_OFF   (VROOT_OFF + NH)         // [0]=loss sum, [1]=done counter (int)

// ---------------------------------------------------------------------------
// Kernel 1: hidden partials, K-split x2.  h_z = C[:, z*256:+256] @ W1[z*256:+256,:]
// 64x64 tile, 4x4/thread, BK=16, reg-staged pipeline (T14): loads for chunk
// c+2 issued before compute(c); double LDS buffer -> 1 barrier per chunk.
// grid (32,4,2) = 256 blocks. bias+relu deferred to K2's A-stage.
// Block (0,0,0) zeroes the loss accumulator + done counter (ws poisoned).
// ---------------------------------------------------------------------------
__global__ __launch_bounds__(256) void gemm_hidden(
    const float* __restrict__ A,   // 2048 x 512
    const float* __restrict__ W,   // 512 x 256
    float* __restrict__ h,         // 2 x 2048 x 256 partials
    float* __restrict__ accum)
{
    __shared__ float As[2][16][68];   // [buf][k][m]
    __shared__ float Bs[2][16][68];   // [buf][k][n]
    int m0 = blockIdx.x * 64;
    int n0 = blockIdx.y * 64;
    int kbase = blockIdx.z * 256;
    int tid = threadIdx.x;
    if (blockIdx.x == 0 && blockIdx.y == 0 && blockIdx.z == 0 && tid == 0) {
        accum[0] = 0.f;
        ((int*)accum)[1] = 0;
    }
    int arow = tid >> 2, akq = (tid & 3) * 4;   // A-stage: 64 rows x 16 k
    int bk = tid >> 4, bn = (tid & 15) * 4;     // B-stage: 16 k x 64 n
    int tm = tid >> 4, tn = tid & 15;           // compute: 4 rows x 4 cols
    float acc[4][4] = {{0.f}};
    float4 a_r, b_r;

    auto LOADK = [&](int c) {
        int k0 = kbase + c * 16;
        a_r = *(const float4*)&A[(size_t)(m0 + arow) * DIN + k0 + akq];
        b_r = *(const float4*)&W[(size_t)(k0 + bk) * NH + n0 + bn];
    };
    auto WRITE = [&](int buf) {
        As[buf][akq + 0][arow] = a_r.x; As[buf][akq + 1][arow] = a_r.y;
        As[buf][akq + 2][arow] = a_r.z; As[buf][akq + 3][arow] = a_r.w;
        *(float4*)&Bs[buf][bk][bn] = b_r;
    };

    LOADK(0);
    WRITE(0);
    LOADK(1);
    __syncthreads();
    for (int c = 0; c < 16; ++c) {
        int buf = c & 1;
        #pragma unroll
        for (int kk = 0; kk < 16; kk++) {
            float4 av = *(const float4*)&As[buf][kk][tm * 4];
            float4 bv = *(const float4*)&Bs[buf][kk][tn * 4];
            float ar[4] = {av.x, av.y, av.z, av.w};
            float br[4] = {bv.x, bv.y, bv.z, bv.w};
            #pragma unroll
            for (int r = 0; r < 4; r++)
                #pragma unroll
                for (int cc = 0; cc < 4; cc++)
                    acc[r][cc] = fmaf(ar[r], br[cc], acc[r][cc]);
        }
        if (c < 15) {
            WRITE(buf ^ 1);          // stage chunk c+1 (loads issued iter c-1)
            if (c < 14) LOADK(c + 2);
            __syncthreads();
        }
    }
    float* hz = h + (size_t)blockIdx.z * NM * NH;
    int col = n0 + tn * 4;
    #pragma unroll
    for (int r = 0; r < 4; r++) {
        int row = m0 + tm * 4 + r;
        *(float4*)&hz[(size_t)row * NH + col] =
            make_float4(acc[r][0], acc[r][1], acc[r][2], acc[r][3]);
    }
}

// ---------------------------------------------------------------------------
// Kernel 2: u = hidden@Wa + bp ; hv = hidden@Wb ; vroot = root@Wb
// hidden reconstructed on the fly: relu(h0 + h1 + b1) during A-stage.
// Full K=256 (no K-split -> single u/hv slabs; bp folded here). 64x64 tile,
// BK=16, reg-staged pipeline as in K1. grid (33,8); x==32 = root rows.
// ---------------------------------------------------------------------------
__global__ __launch_bounds__(256) void gemm_uv(
    const float* __restrict__ h,      // 2 x 2048 x 256 partials
    const float* __restrict__ b1,     // 256 (hidden bias)
    const float* __restrict__ Wp,     // 512 x 256
    const float* __restrict__ bp,     // 256 (pair bias)
    const float* __restrict__ root,   // 256
    float* __restrict__ u,            // 2048 x 256
    float* __restrict__ hv,           // 2048 x 256
    float* __restrict__ vroot)        // 256
{
    __shared__ float As[2][16][68];
    __shared__ float Bs[2][16][68];
    __shared__ float part[4][64];
    int n0 = blockIdx.y * 64;
    int tid = threadIdx.x;

    if (blockIdx.x == 32) {            // root row blocks
        if (n0 < NH) return;
        int col = (n0 - NH) + (tid & 63);
        int kc = tid >> 6;
        float p = 0.f;
        #pragma unroll 8
        for (int c = kc * 64; c < kc * 64 + 64; c++)
            p += root[c] * Wp[(size_t)(NH + c) * NH + col];
        part[kc][tid & 63] = p;
        __syncthreads();
        if (tid < 64)
            vroot[(n0 - NH) + tid] = part[0][tid] + part[1][tid]
                                   + part[2][tid] + part[3][tid];
        return;
    }

    int m0 = blockIdx.x * 64;
    bool isU = (n0 < NH);
    int arow = tid >> 2, akq = (tid & 3) * 4;
    int bk = tid >> 4, bn = (tid & 15) * 4;
    int tm = tid >> 4, tn = tid & 15;
    float acc[4][4] = {{0.f}};
    float4 ha_r, hb_r, bi_r, b_r;

    auto LOADK = [&](int c) {
        int k0 = c * 16;
        size_t base = (size_t)(m0 + arow) * NH + k0 + akq;
        ha_r = *(const float4*)&h[base];
        hb_r = *(const float4*)&h[base + (size_t)NM * NH];
        bi_r = *(const float4*)&b1[k0 + akq];
        int ck = k0 + bk;
        if (isU) b_r = *(const float4*)&Wp[(size_t)ck * NH + n0 + bn];
        else     b_r = *(const float4*)&Wp[(size_t)(NH + ck) * NH + (n0 - NH) + bn];
    };
    auto WRITE = [&](int buf) {
        As[buf][akq + 0][arow] = fmaxf(ha_r.x + hb_r.x + bi_r.x, 0.f);
        As[buf][akq + 1][arow] = fmaxf(ha_r.y + hb_r.y + bi_r.y, 0.f);
        As[buf][akq + 2][arow] = fmaxf(ha_r.z + hb_r.z + bi_r.z, 0.f);
        As[buf][akq + 3][arow] = fmaxf(ha_r.w + hb_r.w + bi_r.w, 0.f);
        *(float4*)&Bs[buf][bk][bn] = b_r;
    };

    LOADK(0);
    WRITE(0);
    LOADK(1);
    __syncthreads();
    for (int c = 0; c < 16; ++c) {
        int buf = c & 1;
        #pragma unroll
        for (int kk = 0; kk < 16; kk++) {
            float4 av = *(const float4*)&As[buf][kk][tm * 4];
            float4 bv = *(const float4*)&Bs[buf][kk][tn * 4];
            float ar[4] = {av.x, av.y, av.z, av.w};
            float br[4] = {bv.x, bv.y, bv.z, bv.w};
            #pragma unroll
            for (int r = 0; r < 4; r++)
                #pragma unroll
                for (int cc = 0; cc < 4; cc++)
                    acc[r][cc] = fmaf(ar[r], br[cc], acc[r][cc]);
        }
        if (c < 15) {
            WRITE(buf ^ 1);
            if (c < 14) LOADK(c + 2);
            __syncthreads();
        }
    }
    if (isU) {
        int col = n0 + tn * 4;
        float4 bb = *(const float4*)&bp[col];
        #pragma unroll
        for (int r = 0; r < 4; r++) {
            int row = m0 + tm * 4 + r;
            *(float4*)&u[(size_t)row * NH + col] = make_float4(
                acc[r][0] + bb.x, acc[r][1] + bb.y,
                acc[r][2] + bb.z, acc[r][3] + bb.w);
        }
    } else {
        int col = (n0 - NH) + tn * 4;
        #pragma unroll
        for (int r = 0; r < 4; r++) {
            int row = m0 + tm * 4 + r;
            *(float4*)&hv[(size_t)row * NH + col] = make_float4(
                acc[r][0], acc[r][1], acc[r][2], acc[r][3]);
        }
    }
}

// ---------------------------------------------------------------------------
// Kernel 3 (fused scores+loss+finalize): round-4 proven structure + T14
// register prefetch of the v chunk. Block = 4 waves = 4 rows; grid (NB,32)
// = 512 blocks. Per k-chunk (64 k): v staged k-major float2 [kk2][j]
// (single hv slab now); loads for chunk c+1 issued before compute(c).
// Lane owns j=lane and j=lane+64; j=128 + sel on lanes<32 k-slices; label
// logits read W_lab direct. One atomicAdd per block; done-counter finalize.
// ---------------------------------------------------------------------------
#define NBLK (NB*32)   // 512

__global__ __launch_bounds__(256) void score_loss_kernel(
    const float* __restrict__ u, const float* __restrict__ hv,
    const float* __restrict__ vroot, const float* __restrict__ W_arc,
    const float* __restrict__ W_lab, const float* __restrict__ b_lab,
    const int* __restrict__ slens, const int* __restrict__ arcs,
    const int* __restrict__ labels,
    float* __restrict__ accum, float* __restrict__ out)
{
    __shared__ float2 v2_s[32][129];   // [kk2][j]  33,024 B
    __shared__ float2 u2_s[4][128];    // [row][kk2] 4,096 B
    __shared__ float2 wa2_s[128];      //            1,024 B
    __shared__ float2 sel2_s[32][5];   // [kk2][row] 1,280 B
    __shared__ float  ce_s[4];
    __shared__ int    arc_s[4], lab_s[4];

    int bb = blockIdx.x;
    int i0 = blockIdx.y * 4;
    int tid = threadIdx.x;
    int w = tid >> 6;          // wave index = local row
    int lane = tid & 63;
    int slen = slens[bb];

    if (i0 < slen) {
        // ---- one-time staging: u rows (bp already folded), W_arc, arcs ----
        {
            int r = tid >> 6, kq = (tid & 63) * 4;
            float4 a4 = *(const float4*)&u[(size_t)(bb * NL + i0 + r) * NH + kq];
            u2_s[r][(kq >> 1) + 0] = make_float2(a4.x, a4.y);
            u2_s[r][(kq >> 1) + 1] = make_float2(a4.z, a4.w);
        }
        if (tid < 128)
            wa2_s[tid] = *(const float2*)&W_arc[tid * 2];
        if (tid < 4) {
            int rg = bb * NL + i0 + tid;
            arc_s[tid] = arcs[rg];
            lab_s[tid] = labels[rg];
        }

        float4 vr[9];
        auto VLOAD = [&](int c) {        // issue chunk-c loads into registers
            int k0 = c * 64;
            #pragma unroll
            for (int s = 0; s < 9; ++s) {
                int idx = tid + s * 256;
                if (idx < NJ * 16) {
                    int j = idx >> 4, kq = (idx & 15) * 4;
                    const float* src = (j == 0) ? (vroot + k0 + kq)
                        : (hv + (size_t)(bb * NL + j - 1) * NH + k0 + kq);
                    vr[s] = *(const float4*)src;
                }
            }
        };
        auto VWRITE = [&]() {            // registers -> LDS (k-major)
            #pragma unroll
            for (int s = 0; s < 9; ++s) {
                int idx = tid + s * 256;
                if (idx < NJ * 16) {
                    int j = idx >> 4, kq = (idx & 15) * 4;
                    v2_s[(kq >> 1) + 0][j] = make_float2(vr[s].x, vr[s].y);
                    v2_s[(kq >> 1) + 1][j] = make_float2(vr[s].z, vr[s].w);
                }
            }
        };

        float acc1 = 0.f, acc2 = 0.f, s128 = 0.f, lacc = 0.f;

        VLOAD(0);
        for (int c = 0; c < 4; ++c) {
            if (c) __syncthreads();      // prev compute done, LDS free
            VWRITE();                    // waits vmcnt (issued last iter)
            __syncthreads();             // v2_s (+u2_s on c=0) visible
            if (c < 3) VLOAD(c + 1);     // issue next; hidden under compute
            int k0 = c * 64;

            // ---- arc scores: lane covers j=lane and j=lane+64 ----
            const float2* urow = u2_s[w] + (k0 >> 1);
            const float2* warow = wa2_s + (k0 >> 1);
            #pragma unroll 8
            for (int kk2 = 0; kk2 < 32; ++kk2) {
                float2 u2 = urow[kk2];
                float2 w2 = warow[kk2];
                float2 va = v2_s[kk2][lane];
                float2 vb = v2_s[kk2][lane + 64];
                acc1 += fmaxf(u2.x + va.x, 0.f) * w2.x
                      + fmaxf(u2.y + va.y, 0.f) * w2.y;
                acc2 += fmaxf(u2.x + vb.x, 0.f) * w2.x
                      + fmaxf(u2.y + vb.y, 0.f) * w2.y;
            }
            // ---- j=128 partial + sel staging (lanes 0..31, kk2=lane) ----
            if (lane < 32) {
                float2 u2 = urow[lane];
                float2 w2 = warow[lane];
                float2 vv = v2_s[lane][128];
                s128 += fmaxf(u2.x + vv.x, 0.f) * w2.x
                      + fmaxf(u2.y + vv.y, 0.f) * w2.y;
                float2 vs = v2_s[lane][arc_s[w]];
                sel2_s[lane][w] = make_float2(fmaxf(u2.x + vs.x, 0.f),
                                              fmaxf(u2.y + vs.y, 0.f));
            }
            // ---- label logit partials: lane = tag, W_lab direct (L1) ----
            if (lane < NTAGS) {
                #pragma unroll 8
                for (int kk2 = 0; kk2 < 32; ++kk2) {
                    float2 s2 = sel2_s[kk2][w];
                    float w0 = W_lab[(size_t)(k0 + 2 * kk2) * NTAGS + lane];
                    float w1 = W_lab[(size_t)(k0 + 2 * kk2 + 1) * NTAGS + lane];
                    lacc = fmaf(s2.x, w0, fmaf(s2.y, w1, lacc));
                }
            }
        }

        // ---- arc softmax CE (full-wave shuffles) ----
        float s128t = s128;
        #pragma unroll
        for (int off = 32; off > 0; off >>= 1)
            s128t += __shfl_xor(s128t, off);
        float m = fmaxf(acc1, acc2);
        #pragma unroll
        for (int off = 32; off > 0; off >>= 1)
            m = fmaxf(m, __shfl_xor(m, off));
        m = fmaxf(m, s128t);
        float e = expf(acc1 - m) + expf(acc2 - m);
        #pragma unroll
        for (int off = 32; off > 0; off >>= 1)
            e += __shfl_xor(e, off);
        e += expf(s128t - m);
        int a = arc_s[w];
        float cand = (a < 64) ? acc1 : acc2;
        float s_a = __shfl(cand, a & 63, 64);
        if (a == 128) s_a = s128t;
        float arc_ce = (m + logf(e)) - s_a;

        // ---- label softmax CE ----
        float logit = (lane < NTAGS) ? (lacc + b_lab[lane]) : -INFINITY;
        float m2 = logit;
        #pragma unroll
        for (int off = 32; off > 0; off >>= 1)
            m2 = fmaxf(m2, __shfl_xor(m2, off));
        float e2 = (lane < NTAGS) ? expf(logit - m2) : 0.f;
        #pragma unroll
        for (int off = 32; off > 0; off >>= 1)
            e2 += __shfl_xor(e2, off);
        float l_t = __shfl(logit, lab_s[w], 64);
        float lab_ce = (m2 + logf(e2)) - l_t;

        float tot = ((i0 + w) < slen) ? (arc_ce + lab_ce) : 0.f;
        if (lane == 0) ce_s[w] = tot;
        __syncthreads();
        if (tid == 0)
            atomicAdd(accum, ce_s[0] + ce_s[1] + ce_s[2] + ce_s[3]);
    }

    // ---- done counter; last block finalizes ----
    if (tid == 0) {
        __threadfence();
        int prev = atomicAdd((int*)accum + 1, 1);
        if (prev == NBLK - 1) {
            int d = 0;
            #pragma unroll
            for (int q = 0; q < NB; ++q) d += slens[q];
            float s = atomicAdd(accum, 0.f);   // coherent read
            out[0] = 0.5f * s / fmaxf((float)d, 1.f);
        }
    }
}

extern "C" void kernel_launch(void* const* d_in, const int* in_sizes, int n_in,
                              void* d_out, int out_size, void* d_ws, size_t ws_size,
                              hipStream_t stream) {
    (void)in_sizes; (void)n_in; (void)out_size; (void)ws_size;
    const float* ctx   = (const float*)d_in[0];
    const int*   slens = (const int*)  d_in[1];
    const int*   arcs  = (const int*)  d_in[2];
    const int*   labs  = (const int*)  d_in[3];
    const float* W1    = (const float*)d_in[4];
    const float* b1    = (const float*)d_in[5];
    const float* root  = (const float*)d_in[6];
    const float* Wp    = (const float*)d_in[7];
    const float* bp    = (const float*)d_in[8];
    const float* W_arc = (const float*)d_in[9];
    // d_in[10] = b_arc: constant shift, cancels in arc log-softmax CE
    const float* W_lab = (const float*)d_in[11];
    const float* b_lab = (const float*)d_in[12];
    float* out = (float*)d_out;

    float* ws    = (float*)d_ws;
    float* h     = ws + H_OFF;
    float* u     = ws + U_OFF;
    float* hv    = ws + HV_OFF;
    float* vroot = ws + VROOT_OFF;
    float* accum = ws + ACC_OFF;

    gemm_hidden<<<dim3(32, 4, 2), 256, 0, stream>>>(ctx, W1, h, accum);
    gemm_uv<<<dim3(33, 8), 256, 0, stream>>>(h, b1, Wp, bp, root, u, hv, vroot);
    score_loss_kernel<<<dim3(NB, 32), 256, 0, stream>>>(
        u, hv, vroot, W_arc, W_lab, b_lab, slens, arcs, labs, accum, out);
}

// Round 8
// 135.784 us; speedup vs baseline: 1.5837x; 1.0286x over previous
//
#include <hip/hip_runtime.h>
#include <math.h>

// Problem constants
#define NB 16
#define NL 128
#define DIN 512
#define NH 256
#define NTAGS 45
#define NM (NB*NL)          // 2048 rows
#define NJ (NL+1)           // 129 arc columns

// ws layout (floats)
#define H_OFF     0                        // 2 slabs of NM*NH (k1 K-split partials)
#define U_OFF     (2*NM*NH)                // 1 slab  (u = hidden@Wa + bp)
#define HV_OFF    (3*NM*NH)                // 1 slab  (hv = hidden@Wb)
#define VROOT_OFF (4*NM*NH)                // NH
#define ACC_OFF   (VROOT_OFF + NH)         // [0]=loss sum, [1]=done counter (int)

// ---------------------------------------------------------------------------
// Kernel 1: hidden partials, K-split x2.  h_z = C[:, z*256:+256] @ W1[z*256:+256,:]
// 64x64 tile, 4x4/thread, BK=16, reg-staged pipeline (T14): loads for chunk
// c+2 issued before compute(c); double LDS buffer -> 1 barrier per chunk.
// grid (32,4,2) = 256 blocks = exactly 1/CU. bias+relu deferred to K2.
// Blocks (x==31, z==1) also compute vroot = root @ Wb as a ~1us epilogue
// (vroot depends only on inputs -> moves the k2 straggler blocks here).
// Block (0,0,0) zeroes the loss accumulator + done counter (ws poisoned).
// ---------------------------------------------------------------------------
__global__ __launch_bounds__(256) void gemm_hidden(
    const float* __restrict__ A,    // 2048 x 512
    const float* __restrict__ W,    // 512 x 256
    const float* __restrict__ Wp,   // 512 x 256 (for vroot epilogue)
    const float* __restrict__ root, // 256
    float* __restrict__ h,          // 2 x 2048 x 256 partials
    float* __restrict__ vroot,      // 256
    float* __restrict__ accum)
{
    __shared__ float As[2][16][68];   // [buf][k][m]
    __shared__ float Bs[2][16][68];   // [buf][k][n]
    __shared__ float part[4][64];     // vroot epilogue scratch
    int m0 = blockIdx.x * 64;
    int n0 = blockIdx.y * 64;
    int kbase = blockIdx.z * 256;
    int tid = threadIdx.x;
    if (blockIdx.x == 0 && blockIdx.y == 0 && blockIdx.z == 0 && tid == 0) {
        accum[0] = 0.f;
        ((int*)accum)[1] = 0;
    }
    int arow = tid >> 2, akq = (tid & 3) * 4;   // A-stage: 64 rows x 16 k
    int bk = tid >> 4, bn = (tid & 15) * 4;     // B-stage: 16 k x 64 n
    int tm = tid >> 4, tn = tid & 15;           // compute: 4 rows x 4 cols
    float acc[4][4] = {{0.f}};
    float4 a_r, b_r;

    auto LOADK = [&](int c) {
        int k0 = kbase + c * 16;
        a_r = *(const float4*)&A[(size_t)(m0 + arow) * DIN + k0 + akq];
        b_r = *(const float4*)&W[(size_t)(k0 + bk) * NH + n0 + bn];
    };
    auto WRITE = [&](int buf) {
        As[buf][akq + 0][arow] = a_r.x; As[buf][akq + 1][arow] = a_r.y;
        As[buf][akq + 2][arow] = a_r.z; As[buf][akq + 3][arow] = a_r.w;
        *(float4*)&Bs[buf][bk][bn] = b_r;
    };

    LOADK(0);
    WRITE(0);
    LOADK(1);
    __syncthreads();
    for (int c = 0; c < 16; ++c) {
        int buf = c & 1;
        #pragma unroll
        for (int kk = 0; kk < 16; kk++) {
            float4 av = *(const float4*)&As[buf][kk][tm * 4];
            float4 bv = *(const float4*)&Bs[buf][kk][tn * 4];
            float ar[4] = {av.x, av.y, av.z, av.w};
            float br[4] = {bv.x, bv.y, bv.z, bv.w};
            #pragma unroll
            for (int r = 0; r < 4; r++)
                #pragma unroll
                for (int cc = 0; cc < 4; cc++)
                    acc[r][cc] = fmaf(ar[r], br[cc], acc[r][cc]);
        }
        if (c < 15) {
            WRITE(buf ^ 1);          // stage chunk c+1 (loads issued iter c-1)
            if (c < 14) LOADK(c + 2);
            __syncthreads();
        }
    }
    float* hz = h + (size_t)blockIdx.z * NM * NH;
    int col = n0 + tn * 4;
    #pragma unroll
    for (int r = 0; r < 4; r++) {
        int row = m0 + tm * 4 + r;
        *(float4*)&hz[(size_t)row * NH + col] =
            make_float4(acc[r][0], acc[r][1], acc[r][2], acc[r][3]);
    }

    // ---- vroot epilogue on 4 blocks (x==31, z==1): cols n0..n0+63 ----
    if (blockIdx.x == 31 && blockIdx.z == 1) {
        __syncthreads();               // protect As/Bs reuse boundary (cheap)
        int vcol = n0 + (tid & 63);
        int kc = tid >> 6;
        float p = 0.f;
        #pragma unroll 8
        for (int c = kc * 64; c < kc * 64 + 64; c++)
            p += root[c] * Wp[(size_t)(NH + c) * NH + vcol];
        part[kc][tid & 63] = p;
        __syncthreads();
        if (tid < 64)
            vroot[n0 + tid] = part[0][tid] + part[1][tid]
                            + part[2][tid] + part[3][tid];
    }
}

// ---------------------------------------------------------------------------
// Kernel 2: u = hidden@Wa + bp ; hv = hidden@Wb
// hidden reconstructed on the fly: relu(h0 + h1 + b1) during A-stage.
// Full K=256 (single u/hv slabs; bp folded here). 64x64 tile, BK=16,
// reg-staged pipeline as in K1. grid (32,8) = 256 blocks = exactly 1/CU
// (root rows moved to K1 -> no straggler tail).
// ---------------------------------------------------------------------------
__global__ __launch_bounds__(256) void gemm_uv(
    const float* __restrict__ h,      // 2 x 2048 x 256 partials
    const float* __restrict__ b1,     // 256 (hidden bias)
    const float* __restrict__ Wp,     // 512 x 256
    const float* __restrict__ bp,     // 256 (pair bias)
    float* __restrict__ u,            // 2048 x 256
    float* __restrict__ hv)           // 2048 x 256
{
    __shared__ float As[2][16][68];
    __shared__ float Bs[2][16][68];
    int n0 = blockIdx.y * 64;
    int tid = threadIdx.x;

    int m0 = blockIdx.x * 64;
    bool isU = (n0 < NH);
    int arow = tid >> 2, akq = (tid & 3) * 4;
    int bk = tid >> 4, bn = (tid & 15) * 4;
    int tm = tid >> 4, tn = tid & 15;
    float acc[4][4] = {{0.f}};
    float4 ha_r, hb_r, bi_r, b_r;

    auto LOADK = [&](int c) {
        int k0 = c * 16;
        size_t base = (size_t)(m0 + arow) * NH + k0 + akq;
        ha_r = *(const float4*)&h[base];
        hb_r = *(const float4*)&h[base + (size_t)NM * NH];
        bi_r = *(const float4*)&b1[k0 + akq];
        int ck = k0 + bk;
        if (isU) b_r = *(const float4*)&Wp[(size_t)ck * NH + n0 + bn];
        else     b_r = *(const float4*)&Wp[(size_t)(NH + ck) * NH + (n0 - NH) + bn];
    };
    auto WRITE = [&](int buf) {
        As[buf][akq + 0][arow] = fmaxf(ha_r.x + hb_r.x + bi_r.x, 0.f);
        As[buf][akq + 1][arow] = fmaxf(ha_r.y + hb_r.y + bi_r.y, 0.f);
        As[buf][akq + 2][arow] = fmaxf(ha_r.z + hb_r.z + bi_r.z, 0.f);
        As[buf][akq + 3][arow] = fmaxf(ha_r.w + hb_r.w + bi_r.w, 0.f);
        *(float4*)&Bs[buf][bk][bn] = b_r;
    };

    LOADK(0);
    WRITE(0);
    LOADK(1);
    __syncthreads();
    for (int c = 0; c < 16; ++c) {
        int buf = c & 1;
        #pragma unroll
        for (int kk = 0; kk < 16; kk++) {
            float4 av = *(const float4*)&As[buf][kk][tm * 4];
            float4 bv = *(const float4*)&Bs[buf][kk][tn * 4];
            float ar[4] = {av.x, av.y, av.z, av.w};
            float br[4] = {bv.x, bv.y, bv.z, bv.w};
            #pragma unroll
            for (int r = 0; r < 4; r++)
                #pragma unroll
                for (int cc = 0; cc < 4; cc++)
                    acc[r][cc] = fmaf(ar[r], br[cc], acc[r][cc]);
        }
        if (c < 15) {
            WRITE(buf ^ 1);
            if (c < 14) LOADK(c + 2);
            __syncthreads();
        }
    }
    if (isU) {
        int col = n0 + tn * 4;
        float4 bb = *(const float4*)&bp[col];
        #pragma unroll
        for (int r = 0; r < 4; r++) {
            int row = m0 + tm * 4 + r;
            *(float4*)&u[(size_t)row * NH + col] = make_float4(
                acc[r][0] + bb.x, acc[r][1] + bb.y,
                acc[r][2] + bb.z, acc[r][3] + bb.w);
        }
    } else {
        int col = (n0 - NH) + tn * 4;
        #pragma unroll
        for (int r = 0; r < 4; r++) {
            int row = m0 + tm * 4 + r;
            *(float4*)&hv[(size_t)row * NH + col] = make_float4(
                acc[r][0], acc[r][1], acc[r][2], acc[r][3]);
        }
    }
}

// ---------------------------------------------------------------------------
// Kernel 3 (fused scores+loss+finalize): round-7 proven structure + T5
// setprio around the compute phases. Block = 4 waves = 4 rows; grid (NB,32)
// = 512 blocks = exactly 2/CU. Per k-chunk (64 k): v staged k-major float2
// [kk2][j]; loads for chunk c+1 issued before compute(c) (T14). Lane owns
// j=lane and j=lane+64; j=128 + sel on lanes<32 k-slices; label logits read
// W_lab direct. One atomicAdd per block; done-counter finalize.
// ---------------------------------------------------------------------------
#define NBLK (NB*32)   // 512

__global__ __launch_bounds__(256) void score_loss_kernel(
    const float* __restrict__ u, const float* __restrict__ hv,
    const float* __restrict__ vroot, const float* __restrict__ W_arc,
    const float* __restrict__ W_lab, const float* __restrict__ b_lab,
    const int* __restrict__ slens, const int* __restrict__ arcs,
    const int* __restrict__ labels,
    float* __restrict__ accum, float* __restrict__ out)
{
    __shared__ float2 v2_s[32][129];   // [kk2][j]  33,024 B
    __shared__ float2 u2_s[4][128];    // [row][kk2] 4,096 B
    __shared__ float2 wa2_s[128];      //            1,024 B
    __shared__ float2 sel2_s[32][5];   // [kk2][row] 1,280 B
    __shared__ float  ce_s[4];
    __shared__ int    arc_s[4], lab_s[4];

    int bb = blockIdx.x;
    int i0 = blockIdx.y * 4;
    int tid = threadIdx.x;
    int w = tid >> 6;          // wave index = local row
    int lane = tid & 63;
    int slen = slens[bb];

    if (i0 < slen) {
        // ---- one-time staging: u rows (bp already folded), W_arc, arcs ----
        {
            int r = tid >> 6, kq = (tid & 63) * 4;
            float4 a4 = *(const float4*)&u[(size_t)(bb * NL + i0 + r) * NH + kq];
            u2_s[r][(kq >> 1) + 0] = make_float2(a4.x, a4.y);
            u2_s[r][(kq >> 1) + 1] = make_float2(a4.z, a4.w);
        }
        if (tid < 128)
            wa2_s[tid] = *(const float2*)&W_arc[tid * 2];
        if (tid < 4) {
            int rg = bb * NL + i0 + tid;
            arc_s[tid] = arcs[rg];
            lab_s[tid] = labels[rg];
        }

        float4 vr[9];
        auto VLOAD = [&](int c) {        // issue chunk-c loads into registers
            int k0 = c * 64;
            #pragma unroll
            for (int s = 0; s < 9; ++s) {
                int idx = tid + s * 256;
                if (idx < NJ * 16) {
                    int j = idx >> 4, kq = (idx & 15) * 4;
                    const float* src = (j == 0) ? (vroot + k0 + kq)
                        : (hv + (size_t)(bb * NL + j - 1) * NH + k0 + kq);
                    vr[s] = *(const float4*)src;
                }
            }
        };
        auto VWRITE = [&]() {            // registers -> LDS (k-major)
            #pragma unroll
            for (int s = 0; s < 9; ++s) {
                int idx = tid + s * 256;
                if (idx < NJ * 16) {
                    int j = idx >> 4, kq = (idx & 15) * 4;
                    v2_s[(kq >> 1) + 0][j] = make_float2(vr[s].x, vr[s].y);
                    v2_s[(kq >> 1) + 1][j] = make_float2(vr[s].z, vr[s].w);
                }
            }
        };

        float acc1 = 0.f, acc2 = 0.f, s128 = 0.f, lacc = 0.f;

        VLOAD(0);
        for (int c = 0; c < 4; ++c) {
            if (c) __syncthreads();      // prev compute done, LDS free
            VWRITE();                    // waits vmcnt (issued last iter)
            __syncthreads();             // v2_s (+u2_s on c=0) visible
            if (c < 3) VLOAD(c + 1);     // issue next; hidden under compute
            int k0 = c * 64;

            __builtin_amdgcn_s_setprio(1);
            // ---- arc scores: lane covers j=lane and j=lane+64 ----
            const float2* urow = u2_s[w] + (k0 >> 1);
            const float2* warow = wa2_s + (k0 >> 1);
            #pragma unroll 8
            for (int kk2 = 0; kk2 < 32; ++kk2) {
                float2 u2 = urow[kk2];
                float2 w2 = warow[kk2];
                float2 va = v2_s[kk2][lane];
                float2 vb = v2_s[kk2][lane + 64];
                acc1 += fmaxf(u2.x + va.x, 0.f) * w2.x
                      + fmaxf(u2.y + va.y, 0.f) * w2.y;
                acc2 += fmaxf(u2.x + vb.x, 0.f) * w2.x
                      + fmaxf(u2.y + vb.y, 0.f) * w2.y;
            }
            // ---- j=128 partial + sel staging (lanes 0..31, kk2=lane) ----
            if (lane < 32) {
                float2 u2 = urow[lane];
                float2 w2 = warow[lane];
                float2 vv = v2_s[lane][128];
                s128 += fmaxf(u2.x + vv.x, 0.f) * w2.x
                      + fmaxf(u2.y + vv.y, 0.f) * w2.y;
                float2 vs = v2_s[lane][arc_s[w]];
                sel2_s[lane][w] = make_float2(fmaxf(u2.x + vs.x, 0.f),
                                              fmaxf(u2.y + vs.y, 0.f));
            }
            // ---- label logit partials: lane = tag, W_lab direct (L1) ----
            if (lane < NTAGS) {
                #pragma unroll 8
                for (int kk2 = 0; kk2 < 32; ++kk2) {
                    float2 s2 = sel2_s[kk2][w];
                    float w0 = W_lab[(size_t)(k0 + 2 * kk2) * NTAGS + lane];
                    float w1 = W_lab[(size_t)(k0 + 2 * kk2 + 1) * NTAGS + lane];
                    lacc = fmaf(s2.x, w0, fmaf(s2.y, w1, lacc));
                }
            }
            __builtin_amdgcn_s_setprio(0);
        }

        // ---- arc softmax CE (full-wave shuffles) ----
        float s128t = s128;
        #pragma unroll
        for (int off = 32; off > 0; off >>= 1)
            s128t += __shfl_xor(s128t, off);
        float m = fmaxf(acc1, acc2);
        #pragma unroll
        for (int off = 32; off > 0; off >>= 1)
            m = fmaxf(m, __shfl_xor(m, off));
        m = fmaxf(m, s128t);
        float e = expf(acc1 - m) + expf(acc2 - m);
        #pragma unroll
        for (int off = 32; off > 0; off >>= 1)
            e += __shfl_xor(e, off);
        e += expf(s128t - m);
        int a = arc_s[w];
        float cand = (a < 64) ? acc1 : acc2;
        float s_a = __shfl(cand, a & 63, 64);
        if (a == 128) s_a = s128t;
        float arc_ce = (m + logf(e)) - s_a;

        // ---- label softmax CE ----
        float logit = (lane < NTAGS) ? (lacc + b_lab[lane]) : -INFINITY;
        float m2 = logit;
        #pragma unroll
        for (int off = 32; off > 0; off >>= 1)
            m2 = fmaxf(m2, __shfl_xor(m2, off));
        float e2 = (lane < NTAGS) ? expf(logit - m2) : 0.f;
        #pragma unroll
        for (int off = 32; off > 0; off >>= 1)
            e2 += __shfl_xor(e2, off);
        float l_t = __shfl(logit, lab_s[w], 64);
        float lab_ce = (m2 + logf(e2)) - l_t;

        float tot = ((i0 + w) < slen) ? (arc_ce + lab_ce) : 0.f;
        if (lane == 0) ce_s[w] = tot;
        __syncthreads();
        if (tid == 0)
            atomicAdd(accum, ce_s[0] + ce_s[1] + ce_s[2] + ce_s[3]);
    }

    // ---- done counter; last block finalizes ----
    if (tid == 0) {
        __threadfence();
        int prev = atomicAdd((int*)accum + 1, 1);
        if (prev == NBLK - 1) {
            int d = 0;
            #pragma unroll
            for (int q = 0; q < NB; ++q) d += slens[q];
            float s = atomicAdd(accum, 0.f);   // coherent read
            out[0] = 0.5f * s / fmaxf((float)d, 1.f);
        }
    }
}

extern "C" void kernel_launch(void* const* d_in, const int* in_sizes, int n_in,
                              void* d_out, int out_size, void* d_ws, size_t ws_size,
                              hipStream_t stream) {
    (void)in_sizes; (void)n_in; (void)out_size; (void)ws_size;
    const float* ctx   = (const float*)d_in[0];
    const int*   slens = (const int*)  d_in[1];
    const int*   arcs  = (const int*)  d_in[2];
    const int*   labs  = (const int*)  d_in[3];
    const float* W1    = (const float*)d_in[4];
    const float* b1    = (const float*)d_in[5];
    const float* root  = (const float*)d_in[6];
    const float* Wp    = (const float*)d_in[7];
    const float* bp    = (const float*)d_in[8];
    const float* W_arc = (const float*)d_in[9];
    // d_in[10] = b_arc: constant shift, cancels in arc log-softmax CE
    const float* W_lab = (const float*)d_in[11];
    const float* b_lab = (const float*)d_in[12];
    float* out = (float*)d_out;

    float* ws    = (float*)d_ws;
    float* h     = ws + H_OFF;
    float* u     = ws + U_OFF;
    float* hv    = ws + HV_OFF;
    float* vroot = ws + VROOT_OFF;
    float* accum = ws + ACC_OFF;

    gemm_hidden<<<dim3(32, 4, 2), 256, 0, stream>>>(ctx, W1, Wp, root, h, vroot, accum);
    gemm_uv<<<dim3(32, 8), 256, 0, stream>>>(h, b1, Wp, bp, u, hv);
    score_loss_kernel<<<dim3(NB, 32), 256, 0, stream>>>(
        u, hv, vroot, W_arc, W_lab, b_lab, slens, arcs, labs, accum, out);
}

// Round 9
// 130.094 us; speedup vs baseline: 1.6530x; 1.0437x over previous
//
#include <hip/hip_runtime.h>
#include <math.h>

// Problem constants
#define NB 16
#define NL 128
#define DIN 512
#define NH 256
#define NTAGS 45
#define NM (NB*NL)          // 2048 rows
#define NJ (NL+1)           // 129 arc columns

// ws layout (floats)
#define H_OFF     0                        // 2 slabs of NM*NH (k1 K-split partials)
#define U_OFF     (2*NM*NH)                // 1 slab  (u = hidden@Wa + bp)
#define HV_OFF    (3*NM*NH)                // 1 slab  (hv = hidden@Wb)
#define VROOT_OFF (4*NM*NH)                // NH
#define ACC_OFF   (VROOT_OFF + NH)         // [0]=loss sum, [1]=done counter (int)

// ---------------------------------------------------------------------------
// Kernel 1: hidden partials, K-split x2.  h_z = C[:, z*256:+256] @ W1[z*256:+256,:]
// 32x64 tile, 2x4/thread, BK=16, reg-staged dbuf pipeline. grid (64,4,2) =
// 512 blocks -> 2 blocks/CU, 2 waves/SIMD (was 1 -> latency now hidden by TLP).
// bias+relu deferred to K2. Blocks (x==63, z==1) append the vroot epilogue
// (vroot = root @ Wb depends only on inputs). Block 0 zeroes accum+counter.
// ---------------------------------------------------------------------------
__global__ __launch_bounds__(256) void gemm_hidden(
    const float* __restrict__ A,    // 2048 x 512
    const float* __restrict__ W,    // 512 x 256
    const float* __restrict__ Wp,   // 512 x 256 (for vroot epilogue)
    const float* __restrict__ root, // 256
    float* __restrict__ h,          // 2 x 2048 x 256 partials
    float* __restrict__ vroot,      // 256
    float* __restrict__ accum)
{
    __shared__ float As[2][16][36];   // [buf][k][m], m=32 (+4 pad)
    __shared__ float Bs[2][16][68];   // [buf][k][n], n=64 (+4 pad)
    __shared__ float part[4][64];     // vroot epilogue scratch
    int m0 = blockIdx.x * 32;
    int n0 = blockIdx.y * 64;
    int kbase = blockIdx.z * 256;
    int tid = threadIdx.x;
    if (blockIdx.x == 0 && blockIdx.y == 0 && blockIdx.z == 0 && tid == 0) {
        accum[0] = 0.f;
        ((int*)accum)[1] = 0;
    }
    int lm = tid >> 2, lk = (tid & 3) * 4;      // A-stage (tid<128): 32 rows x 16 k
    int bk = tid >> 4, bn = (tid & 15) * 4;     // B-stage: 16 k x 64 n
    int tm = tid >> 4, tn = tid & 15;           // compute: 2 rows x 4 cols
    float acc[2][4] = {{0.f}};
    float4 a_r, b_r;

    auto LOADK = [&](int c) {
        int k0 = kbase + c * 16;
        if (tid < 128)
            a_r = *(const float4*)&A[(size_t)(m0 + lm) * DIN + k0 + lk];
        b_r = *(const float4*)&W[(size_t)(k0 + bk) * NH + n0 + bn];
    };
    auto WRITE = [&](int buf) {
        if (tid < 128) {
            As[buf][lk + 0][lm] = a_r.x; As[buf][lk + 1][lm] = a_r.y;
            As[buf][lk + 2][lm] = a_r.z; As[buf][lk + 3][lm] = a_r.w;
        }
        *(float4*)&Bs[buf][bk][bn] = b_r;
    };

    LOADK(0);
    WRITE(0);
    LOADK(1);
    __syncthreads();
    for (int c = 0; c < 16; ++c) {
        int buf = c & 1;
        #pragma unroll
        for (int kk = 0; kk < 16; kk++) {
            float2 a2 = *(const float2*)&As[buf][kk][tm * 2];
            float4 bv = *(const float4*)&Bs[buf][kk][tn * 4];
            float ar[2] = {a2.x, a2.y};
            float br[4] = {bv.x, bv.y, bv.z, bv.w};
            #pragma unroll
            for (int r = 0; r < 2; r++)
                #pragma unroll
                for (int cc = 0; cc < 4; cc++)
                    acc[r][cc] = fmaf(ar[r], br[cc], acc[r][cc]);
        }
        if (c < 15) {
            WRITE(buf ^ 1);          // stage chunk c+1 (loads issued iter c-1)
            if (c < 14) LOADK(c + 2);
            __syncthreads();
        }
    }
    float* hz = h + (size_t)blockIdx.z * NM * NH;
    int col = n0 + tn * 4;
    #pragma unroll
    for (int r = 0; r < 2; r++) {
        int row = m0 + tm * 2 + r;
        *(float4*)&hz[(size_t)row * NH + col] =
            make_float4(acc[r][0], acc[r][1], acc[r][2], acc[r][3]);
    }

    // ---- vroot epilogue on 4 blocks (x==63, z==1): cols n0..n0+63 ----
    if (blockIdx.x == 63 && blockIdx.z == 1) {
        __syncthreads();
        int vcol = n0 + (tid & 63);
        int kc = tid >> 6;
        float p = 0.f;
        #pragma unroll 8
        for (int c = kc * 64; c < kc * 64 + 64; c++)
            p += root[c] * Wp[(size_t)(NH + c) * NH + vcol];
        part[kc][tid & 63] = p;
        __syncthreads();
        if (tid < 64)
            vroot[n0 + tid] = part[0][tid] + part[1][tid]
                            + part[2][tid] + part[3][tid];
    }
}

// ---------------------------------------------------------------------------
// Kernel 2: u = hidden@Wa + bp ; hv = hidden@Wb
// hidden reconstructed on the fly: relu(h0 + h1 + b1) during A-stage.
// Full K=256 (single u/hv slabs; bp folded). 64x32 tile, 2x4/thread, BK=16,
// reg-staged dbuf pipeline. grid (32,16) = 512 blocks -> 2 blocks/CU,
// 2 waves/SIMD (was 1).
// ---------------------------------------------------------------------------
__global__ __launch_bounds__(256) void gemm_uv(
    const float* __restrict__ h,      // 2 x 2048 x 256 partials
    const float* __restrict__ b1,     // 256 (hidden bias)
    const float* __restrict__ Wp,     // 512 x 256
    const float* __restrict__ bp,     // 256 (pair bias)
    float* __restrict__ u,            // 2048 x 256
    float* __restrict__ hv)           // 2048 x 256
{
    __shared__ float As[2][16][68];   // [buf][k][m], m=64 (+4 pad)
    __shared__ float Bs[2][16][36];   // [buf][k][n], n=32 (+4 pad)
    int m0 = blockIdx.x * 64;
    int n0 = blockIdx.y * 32;
    int tid = threadIdx.x;
    bool isU = (n0 < NH);
    int arow = tid >> 2, akq = (tid & 3) * 4;   // A-stage: 64 rows x 16 k
    int bk = tid >> 3, bn = (tid & 7) * 4;      // B-stage (tid<128): 16 k x 32 n
    int tm = tid >> 3, tn = tid & 7;            // compute: 2 rows x 4 cols
    float acc[2][4] = {{0.f}};
    float4 ha_r, hb_r, bi_r, b_r;

    auto LOADK = [&](int c) {
        int k0 = c * 16;
        size_t base = (size_t)(m0 + arow) * NH + k0 + akq;
        ha_r = *(const float4*)&h[base];
        hb_r = *(const float4*)&h[base + (size_t)NM * NH];
        bi_r = *(const float4*)&b1[k0 + akq];
        if (tid < 128) {
            int ck = k0 + bk;
            if (isU) b_r = *(const float4*)&Wp[(size_t)ck * NH + n0 + bn];
            else     b_r = *(const float4*)&Wp[(size_t)(NH + ck) * NH + (n0 - NH) + bn];
        }
    };
    auto WRITE = [&](int buf) {
        As[buf][akq + 0][arow] = fmaxf(ha_r.x + hb_r.x + bi_r.x, 0.f);
        As[buf][akq + 1][arow] = fmaxf(ha_r.y + hb_r.y + bi_r.y, 0.f);
        As[buf][akq + 2][arow] = fmaxf(ha_r.z + hb_r.z + bi_r.z, 0.f);
        As[buf][akq + 3][arow] = fmaxf(ha_r.w + hb_r.w + bi_r.w, 0.f);
        if (tid < 128)
            *(float4*)&Bs[buf][bk][bn] = b_r;
    };

    LOADK(0);
    WRITE(0);
    LOADK(1);
    __syncthreads();
    for (int c = 0; c < 16; ++c) {
        int buf = c & 1;
        #pragma unroll
        for (int kk = 0; kk < 16; kk++) {
            float2 a2 = *(const float2*)&As[buf][kk][tm * 2];
            float4 bv = *(const float4*)&Bs[buf][kk][tn * 4];
            float ar[2] = {a2.x, a2.y};
            float br[4] = {bv.x, bv.y, bv.z, bv.w};
            #pragma unroll
            for (int r = 0; r < 2; r++)
                #pragma unroll
                for (int cc = 0; cc < 4; cc++)
                    acc[r][cc] = fmaf(ar[r], br[cc], acc[r][cc]);
        }
        if (c < 15) {
            WRITE(buf ^ 1);
            if (c < 14) LOADK(c + 2);
            __syncthreads();
        }
    }
    if (isU) {
        int col = n0 + tn * 4;
        float4 bb = *(const float4*)&bp[col];
        #pragma unroll
        for (int r = 0; r < 2; r++) {
            int row = m0 + tm * 2 + r;
            *(float4*)&u[(size_t)row * NH + col] = make_float4(
                acc[r][0] + bb.x, acc[r][1] + bb.y,
                acc[r][2] + bb.z, acc[r][3] + bb.w);
        }
    } else {
        int col = (n0 - NH) + tn * 4;
        #pragma unroll
        for (int r = 0; r < 2; r++) {
            int row = m0 + tm * 2 + r;
            *(float4*)&hv[(size_t)row * NH + col] = make_float4(
                acc[r][0], acc[r][1], acc[r][2], acc[r][3]);
        }
    }
}

// ---------------------------------------------------------------------------
// Kernel 3 (fused scores+loss+finalize): 8 rows/block (512 threads = 8 waves,
// wave = row), grid (NB,16) = 256 blocks. The v-tile is staged once per
// 8 rows (stage traffic halved vs 4-row blocks). Per k-chunk (64 k): v staged
// k-major float2 [kk2][j]; T14 register prefetch of chunk c+1 under compute;
// T5 setprio around compute. Lane owns j=lane and j=lane+64; j=128 + sel on
// lanes<32 k-slices; label logits read W_lab direct. One atomicAdd per
// block; done-counter finalize.
// ---------------------------------------------------------------------------
#define NBLK (NB*16)   // 256

__global__ __launch_bounds__(512) void score_loss_kernel(
    const float* __restrict__ u, const float* __restrict__ hv,
    const float* __restrict__ vroot, const float* __restrict__ W_arc,
    const float* __restrict__ W_lab, const float* __restrict__ b_lab,
    const int* __restrict__ slens, const int* __restrict__ arcs,
    const int* __restrict__ labels,
    float* __restrict__ accum, float* __restrict__ out)
{
    __shared__ float2 v2_s[32][129];   // [kk2][j]   33,024 B
    __shared__ float2 u2_s[8][128];    // [row][kk2]  8,192 B
    __shared__ float2 wa2_s[128];      //             1,024 B
    __shared__ float2 sel2_s[32][9];   // [kk2][row]  2,304 B
    __shared__ float  ce_s[8];
    __shared__ int    arc_s[8], lab_s[8];

    int bb = blockIdx.x;
    int i0 = blockIdx.y * 8;
    int tid = threadIdx.x;
    int w = tid >> 6;          // wave index = local row (0..7)
    int lane = tid & 63;
    int slen = slens[bb];

    if (i0 < slen) {
        // ---- one-time staging: u rows (bp already folded), W_arc, arcs ----
        {
            int r = tid >> 6, kq = (tid & 63) * 4;   // 8 rows x 64 float4
            float4 a4 = *(const float4*)&u[(size_t)(bb * NL + i0 + r) * NH + kq];
            u2_s[r][(kq >> 1) + 0] = make_float2(a4.x, a4.y);
            u2_s[r][(kq >> 1) + 1] = make_float2(a4.z, a4.w);
        }
        if (tid < 128)
            wa2_s[tid] = *(const float2*)&W_arc[tid * 2];
        if (tid < 8) {
            int rg = bb * NL + i0 + tid;
            arc_s[tid] = arcs[rg];
            lab_s[tid] = labels[rg];
        }

        float4 vr[5];
        auto VLOAD = [&](int c) {        // issue chunk-c loads into registers
            int k0 = c * 64;
            #pragma unroll
            for (int s = 0; s < 5; ++s) {
                int idx = tid + s * 512;
                if (idx < NJ * 16) {
                    int j = idx >> 4, kq = (idx & 15) * 4;
                    const float* src = (j == 0) ? (vroot + k0 + kq)
                        : (hv + (size_t)(bb * NL + j - 1) * NH + k0 + kq);
                    vr[s] = *(const float4*)src;
                }
            }
        };
        auto VWRITE = [&]() {            // registers -> LDS (k-major)
            #pragma unroll
            for (int s = 0; s < 5; ++s) {
                int idx = tid + s * 512;
                if (idx < NJ * 16) {
                    int j = idx >> 4, kq = (idx & 15) * 4;
                    v2_s[(kq >> 1) + 0][j] = make_float2(vr[s].x, vr[s].y);
                    v2_s[(kq >> 1) + 1][j] = make_float2(vr[s].z, vr[s].w);
                }
            }
        };

        float acc1 = 0.f, acc2 = 0.f, s128 = 0.f, lacc = 0.f;

        VLOAD(0);
        for (int c = 0; c < 4; ++c) {
            if (c) __syncthreads();      // prev compute done, LDS free
            VWRITE();                    // waits vmcnt (issued last iter)
            __syncthreads();             // v2_s (+u2_s on c=0) visible
            if (c < 3) VLOAD(c + 1);     // issue next; hidden under compute
            int k0 = c * 64;

            __builtin_amdgcn_s_setprio(1);
            // ---- arc scores: lane covers j=lane and j=lane+64 ----
            const float2* urow = u2_s[w] + (k0 >> 1);
            const float2* warow = wa2_s + (k0 >> 1);
            #pragma unroll 8
            for (int kk2 = 0; kk2 < 32; ++kk2) {
                float2 u2 = urow[kk2];
                float2 w2 = warow[kk2];
                float2 va = v2_s[kk2][lane];
                float2 vb = v2_s[kk2][lane + 64];
                acc1 += fmaxf(u2.x + va.x, 0.f) * w2.x
                      + fmaxf(u2.y + va.y, 0.f) * w2.y;
                acc2 += fmaxf(u2.x + vb.x, 0.f) * w2.x
                      + fmaxf(u2.y + vb.y, 0.f) * w2.y;
            }
            // ---- j=128 partial + sel staging (lanes 0..31, kk2=lane) ----
            if (lane < 32) {
                float2 u2 = urow[lane];
                float2 w2 = warow[lane];
                float2 vv = v2_s[lane][128];
                s128 += fmaxf(u2.x + vv.x, 0.f) * w2.x
                      + fmaxf(u2.y + vv.y, 0.f) * w2.y;
                float2 vs = v2_s[lane][arc_s[w]];
                sel2_s[lane][w] = make_float2(fmaxf(u2.x + vs.x, 0.f),
                                              fmaxf(u2.y + vs.y, 0.f));
            }
            // ---- label logit partials: lane = tag, W_lab direct (L1) ----
            if (lane < NTAGS) {
                #pragma unroll 8
                for (int kk2 = 0; kk2 < 32; ++kk2) {
                    float2 s2 = sel2_s[kk2][w];
                    float w0 = W_lab[(size_t)(k0 + 2 * kk2) * NTAGS + lane];
                    float w1 = W_lab[(size_t)(k0 + 2 * kk2 + 1) * NTAGS + lane];
                    lacc = fmaf(s2.x, w0, fmaf(s2.y, w1, lacc));
                }
            }
            __builtin_amdgcn_s_setprio(0);
        }

        // ---- arc softmax CE (full-wave shuffles) ----
        float s128t = s128;
        #pragma unroll
        for (int off = 32; off > 0; off >>= 1)
            s128t += __shfl_xor(s128t, off);
        float m = fmaxf(acc1, acc2);
        #pragma unroll
        for (int off = 32; off > 0; off >>= 1)
            m = fmaxf(m, __shfl_xor(m, off));
        m = fmaxf(m, s128t);
        float e = expf(acc1 - m) + expf(acc2 - m);
        #pragma unroll
        for (int off = 32; off > 0; off >>= 1)
            e += __shfl_xor(e, off);
        e += expf(s128t - m);
        int a = arc_s[w];
        float cand = (a < 64) ? acc1 : acc2;
        float s_a = __shfl(cand, a & 63, 64);
        if (a == 128) s_a = s128t;
        float arc_ce = (m + logf(e)) - s_a;

        // ---- label softmax CE ----
        float logit = (lane < NTAGS) ? (lacc + b_lab[lane]) : -INFINITY;
        float m2 = logit;
        #pragma unroll
        for (int off = 32; off > 0; off >>= 1)
            m2 = fmaxf(m2, __shfl_xor(m2, off));
        float e2 = (lane < NTAGS) ? expf(logit - m2) : 0.f;
        #pragma unroll
        for (int off = 32; off > 0; off >>= 1)
            e2 += __shfl_xor(e2, off);
        float l_t = __shfl(logit, lab_s[w], 64);
        float lab_ce = (m2 + logf(e2)) - l_t;

        float tot = ((i0 + w) < slen) ? (arc_ce + lab_ce) : 0.f;
        if (lane == 0) ce_s[w] = tot;
        __syncthreads();
        if (tid == 0)
            atomicAdd(accum, ce_s[0] + ce_s[1] + ce_s[2] + ce_s[3]
                           + ce_s[4] + ce_s[5] + ce_s[6] + ce_s[7]);
    }

    // ---- done counter; last block finalizes ----
    if (tid == 0) {
        __threadfence();
        int prev = atomicAdd((int*)accum + 1, 1);
        if (prev == NBLK - 1) {
            int d = 0;
            #pragma unroll
            for (int q = 0; q < NB; ++q) d += slens[q];
            float s = atomicAdd(accum, 0.f);   // coherent read
            out[0] = 0.5f * s / fmaxf((float)d, 1.f);
        }
    }
}

extern "C" void kernel_launch(void* const* d_in, const int* in_sizes, int n_in,
                              void* d_out, int out_size, void* d_ws, size_t ws_size,
                              hipStream_t stream) {
    (void)in_sizes; (void)n_in; (void)out_size; (void)ws_size;
    const float* ctx   = (const float*)d_in[0];
    const int*   slens = (const int*)  d_in[1];
    const int*   arcs  = (const int*)  d_in[2];
    const int*   labs  = (const int*)  d_in[3];
    const float* W1    = (const float*)d_in[4];
    const float* b1    = (const float*)d_in[5];
    const float* root  = (const float*)d_in[6];
    const float* Wp    = (const float*)d_in[7];
    const float* bp    = (const float*)d_in[8];
    const float* W_arc = (const float*)d_in[9];
    // d_in[10] = b_arc: constant shift, cancels in arc log-softmax CE
    const float* W_lab = (const float*)d_in[11];
    const float* b_lab = (const float*)d_in[12];
    float* out = (float*)d_out;

    float* ws    = (float*)d_ws;
    float* h     = ws + H_OFF;
    float* u     = ws + U_OFF;
    float* hv    = ws + HV_OFF;
    float* vroot = ws + VROOT_OFF;
    float* accum = ws + ACC_OFF;

    gemm_hidden<<<dim3(64, 4, 2), 256, 0, stream>>>(ctx, W1, Wp, root, h, vroot, accum);
    gemm_uv<<<dim3(32, 16), 256, 0, stream>>>(h, b1, Wp, bp, u, hv);
    score_loss_kernel<<<dim3(NB, 16), 512, 0, stream>>>(
        u, hv, vroot, W_arc, W_lab, b_lab, slens, arcs, labs, accum, out);
}

// Round 10
// 128.907 us; speedup vs baseline: 1.6682x; 1.0092x over previous
//
#include <hip/hip_runtime.h>
#include <math.h>

// Problem constants
#define NB 16
#define NL 128
#define DIN 512
#define NH 256
#define NTAGS 45
#define NM (NB*NL)          // 2048 rows
#define NJ (NL+1)           // 129 arc columns

// ws layout (floats)
#define H_OFF     0                        // 2 slabs of NM*NH (k1 K-split partials)
#define U_OFF     (2*NM*NH)                // 1 slab  (u = hidden@Wa + bp)
#define HV_OFF    (3*NM*NH)                // 1 slab  (hv = hidden@Wb)
#define VROOT_OFF (4*NM*NH)                // NH
#define ACC_OFF   (VROOT_OFF + NH)         // [0]=loss sum, [1]=done counter (int)

// ---------------------------------------------------------------------------
// Kernel 1: hidden partials, K-split x2.  h_z = C[:, z*256:+256] @ W1[z*256:+256,:]
// 32x64 tile, 2x4/thread, BK=16, reg-staged dbuf pipeline. grid (64,4,2) =
// 512 blocks -> 2 blocks/CU, 2 waves/SIMD. bias+relu deferred to K2.
// Blocks (x==63, z==1) append the vroot epilogue. Block 0 zeroes accum+counter.
// ---------------------------------------------------------------------------
__global__ __launch_bounds__(256) void gemm_hidden(
    const float* __restrict__ A,    // 2048 x 512
    const float* __restrict__ W,    // 512 x 256
    const float* __restrict__ Wp,   // 512 x 256 (for vroot epilogue)
    const float* __restrict__ root, // 256
    float* __restrict__ h,          // 2 x 2048 x 256 partials
    float* __restrict__ vroot,      // 256
    float* __restrict__ accum)
{
    __shared__ float As[2][16][36];   // [buf][k][m], m=32 (+4 pad)
    __shared__ float Bs[2][16][68];   // [buf][k][n], n=64 (+4 pad)
    __shared__ float part[4][64];     // vroot epilogue scratch
    int m0 = blockIdx.x * 32;
    int n0 = blockIdx.y * 64;
    int kbase = blockIdx.z * 256;
    int tid = threadIdx.x;
    if (blockIdx.x == 0 && blockIdx.y == 0 && blockIdx.z == 0 && tid == 0) {
        accum[0] = 0.f;
        ((int*)accum)[1] = 0;
    }
    int lm = tid >> 2, lk = (tid & 3) * 4;      // A-stage (tid<128): 32 rows x 16 k
    int bk = tid >> 4, bn = (tid & 15) * 4;     // B-stage: 16 k x 64 n
    int tm = tid >> 4, tn = tid & 15;           // compute: 2 rows x 4 cols
    float acc[2][4] = {{0.f}};
    float4 a_r, b_r;

    auto LOADK = [&](int c) {
        int k0 = kbase + c * 16;
        if (tid < 128)
            a_r = *(const float4*)&A[(size_t)(m0 + lm) * DIN + k0 + lk];
        b_r = *(const float4*)&W[(size_t)(k0 + bk) * NH + n0 + bn];
    };
    auto WRITE = [&](int buf) {
        if (tid < 128) {
            As[buf][lk + 0][lm] = a_r.x; As[buf][lk + 1][lm] = a_r.y;
            As[buf][lk + 2][lm] = a_r.z; As[buf][lk + 3][lm] = a_r.w;
        }
        *(float4*)&Bs[buf][bk][bn] = b_r;
    };

    LOADK(0);
    WRITE(0);
    LOADK(1);
    __syncthreads();
    for (int c = 0; c < 16; ++c) {
        int buf = c & 1;
        #pragma unroll
        for (int kk = 0; kk < 16; kk++) {
            float2 a2 = *(const float2*)&As[buf][kk][tm * 2];
            float4 bv = *(const float4*)&Bs[buf][kk][tn * 4];
            float ar[2] = {a2.x, a2.y};
            float br[4] = {bv.x, bv.y, bv.z, bv.w};
            #pragma unroll
            for (int r = 0; r < 2; r++)
                #pragma unroll
                for (int cc = 0; cc < 4; cc++)
                    acc[r][cc] = fmaf(ar[r], br[cc], acc[r][cc]);
        }
        if (c < 15) {
            WRITE(buf ^ 1);          // stage chunk c+1 (loads issued iter c-1)
            if (c < 14) LOADK(c + 2);
            __syncthreads();
        }
    }
    float* hz = h + (size_t)blockIdx.z * NM * NH;
    int col = n0 + tn * 4;
    #pragma unroll
    for (int r = 0; r < 2; r++) {
        int row = m0 + tm * 2 + r;
        *(float4*)&hz[(size_t)row * NH + col] =
            make_float4(acc[r][0], acc[r][1], acc[r][2], acc[r][3]);
    }

    // ---- vroot epilogue on 4 blocks (x==63, z==1): cols n0..n0+63 ----
    if (blockIdx.x == 63 && blockIdx.z == 1) {
        __syncthreads();
        int vcol = n0 + (tid & 63);
        int kc = tid >> 6;
        float p = 0.f;
        #pragma unroll 8
        for (int c = kc * 64; c < kc * 64 + 64; c++)
            p += root[c] * Wp[(size_t)(NH + c) * NH + vcol];
        part[kc][tid & 63] = p;
        __syncthreads();
        if (tid < 64)
            vroot[n0 + tid] = part[0][tid] + part[1][tid]
                            + part[2][tid] + part[3][tid];
    }
}

// ---------------------------------------------------------------------------
// Kernel 2: u = hidden@Wa + bp ; hv = hidden@Wb
// hidden reconstructed on the fly: relu(h0 + h1 + b1) during A-stage.
// Full K=256 (single u/hv slabs; bp folded). 64x32 tile, 2x4/thread, BK=16,
// reg-staged dbuf pipeline. grid (32,16) = 512 blocks -> 2 blocks/CU.
// ---------------------------------------------------------------------------
__global__ __launch_bounds__(256) void gemm_uv(
    const float* __restrict__ h,      // 2 x 2048 x 256 partials
    const float* __restrict__ b1,     // 256 (hidden bias)
    const float* __restrict__ Wp,     // 512 x 256
    const float* __restrict__ bp,     // 256 (pair bias)
    float* __restrict__ u,            // 2048 x 256
    float* __restrict__ hv)           // 2048 x 256
{
    __shared__ float As[2][16][68];   // [buf][k][m], m=64 (+4 pad)
    __shared__ float Bs[2][16][36];   // [buf][k][n], n=32 (+4 pad)
    int m0 = blockIdx.x * 64;
    int n0 = blockIdx.y * 32;
    int tid = threadIdx.x;
    bool isU = (n0 < NH);
    int arow = tid >> 2, akq = (tid & 3) * 4;   // A-stage: 64 rows x 16 k
    int bk = tid >> 3, bn = (tid & 7) * 4;      // B-stage (tid<128): 16 k x 32 n
    int tm = tid >> 3, tn = tid & 7;            // compute: 2 rows x 4 cols
    float acc[2][4] = {{0.f}};
    float4 ha_r, hb_r, bi_r, b_r;

    auto LOADK = [&](int c) {
        int k0 = c * 16;
        size_t base = (size_t)(m0 + arow) * NH + k0 + akq;
        ha_r = *(const float4*)&h[base];
        hb_r = *(const float4*)&h[base + (size_t)NM * NH];
        bi_r = *(const float4*)&b1[k0 + akq];
        if (tid < 128) {
            int ck = k0 + bk;
            if (isU) b_r = *(const float4*)&Wp[(size_t)ck * NH + n0 + bn];
            else     b_r = *(const float4*)&Wp[(size_t)(NH + ck) * NH + (n0 - NH) + bn];
        }
    };
    auto WRITE = [&](int buf) {
        As[buf][akq + 0][arow] = fmaxf(ha_r.x + hb_r.x + bi_r.x, 0.f);
        As[buf][akq + 1][arow] = fmaxf(ha_r.y + hb_r.y + bi_r.y, 0.f);
        As[buf][akq + 2][arow] = fmaxf(ha_r.z + hb_r.z + bi_r.z, 0.f);
        As[buf][akq + 3][arow] = fmaxf(ha_r.w + hb_r.w + bi_r.w, 0.f);
        if (tid < 128)
            *(float4*)&Bs[buf][bk][bn] = b_r;
    };

    LOADK(0);
    WRITE(0);
    LOADK(1);
    __syncthreads();
    for (int c = 0; c < 16; ++c) {
        int buf = c & 1;
        #pragma unroll
        for (int kk = 0; kk < 16; kk++) {
            float2 a2 = *(const float2*)&As[buf][kk][tm * 2];
            float4 bv = *(const float4*)&Bs[buf][kk][tn * 4];
            float ar[2] = {a2.x, a2.y};
            float br[4] = {bv.x, bv.y, bv.z, bv.w};
            #pragma unroll
            for (int r = 0; r < 2; r++)
                #pragma unroll
                for (int cc = 0; cc < 4; cc++)
                    acc[r][cc] = fmaf(ar[r], br[cc], acc[r][cc]);
        }
        if (c < 15) {
            WRITE(buf ^ 1);
            if (c < 14) LOADK(c + 2);
            __syncthreads();
        }
    }
    if (isU) {
        int col = n0 + tn * 4;
        float4 bb = *(const float4*)&bp[col];
        #pragma unroll
        for (int r = 0; r < 2; r++) {
            int row = m0 + tm * 2 + r;
            *(float4*)&u[(size_t)row * NH + col] = make_float4(
                acc[r][0] + bb.x, acc[r][1] + bb.y,
                acc[r][2] + bb.z, acc[r][3] + bb.w);
        }
    } else {
        int col = (n0 - NH) + tn * 4;
        #pragma unroll
        for (int r = 0; r < 2; r++) {
            int row = m0 + tm * 2 + r;
            *(float4*)&hv[(size_t)row * NH + col] = make_float4(
                acc[r][0], acc[r][1], acc[r][2], acc[r][3]);
        }
    }
}

// ---------------------------------------------------------------------------
// Kernel 3 (fused scores+loss+finalize): SINGLE-STAGE full-LDS variant.
// 8 rows/block (512 threads = 8 waves, wave = row), grid (NB,16) = 256
// blocks = 1/CU (LDS-bound anyway: 143.7 KB < 160 KB, precedent m201=128KB).
// The ENTIRE v-tile (129 x 256 = 132 KB, k-major float2 [kk2][j]) is staged
// ONCE -> 2 barriers total (was 8); the 4 k-chunks then run as one
// uninterrupted compute stretch. Stage mapping: per wave 4 j-rows x 16
// float4-cols -> 256B-coalesced global reads AND 2-way (free) LDS writes.
// sel2_s write->read->overwrite is same-wave (DS pipe is in-order per wave).
// Lane owns j=lane and j=lane+64; j=128 + sel on lanes<32 k-slices; label
// logits read W_lab direct. One atomicAdd per block; done-counter finalize.
// ---------------------------------------------------------------------------
#define NBLK (NB*16)   // 256

__global__ __launch_bounds__(512) void score_loss_kernel(
    const float* __restrict__ u, const float* __restrict__ hv,
    const float* __restrict__ vroot, const float* __restrict__ W_arc,
    const float* __restrict__ W_lab, const float* __restrict__ b_lab,
    const int* __restrict__ slens, const int* __restrict__ arcs,
    const int* __restrict__ labels,
    float* __restrict__ accum, float* __restrict__ out)
{
    __shared__ float2 v2_s[128][129];  // [kk2][j]  132,096 B (full K)
    __shared__ float2 u2_s[8][128];    // [row][kk2]  8,192 B
    __shared__ float2 wa2_s[128];      //             1,024 B
    __shared__ float2 sel2_s[32][9];   // [kk2][row]  2,304 B (reused per chunk)
    __shared__ float  ce_s[8];
    __shared__ int    arc_s[8], lab_s[8];

    int bb = blockIdx.x;
    int i0 = blockIdx.y * 8;
    int tid = threadIdx.x;
    int w = tid >> 6;          // wave index = local row (0..7)
    int lane = tid & 63;
    int slen = slens[bb];

    if (i0 < slen) {
        // ---- one-time staging: u rows, W_arc, arcs/labels ----
        {
            int r = tid >> 6, kq = (tid & 63) * 4;   // 8 rows x 64 float4
            float4 a4 = *(const float4*)&u[(size_t)(bb * NL + i0 + r) * NH + kq];
            u2_s[r][(kq >> 1) + 0] = make_float2(a4.x, a4.y);
            u2_s[r][(kq >> 1) + 1] = make_float2(a4.z, a4.w);
        }
        if (tid < 128)
            wa2_s[tid] = *(const float2*)&W_arc[tid * 2];
        if (tid < 8) {
            int rg = bb * NL + i0 + tid;
            arc_s[tid] = arcs[rg];
            lab_s[tid] = labels[rg];
        }

        // ---- v stage (once): hv rows 0..127 -> v cols 1..128; vroot -> col 0.
        // Per wave: 4 j-rows x 16 float4-cols per (sj,sk) step.
        {
            int jo  = lane >> 4;         // 0..3
            int kf0 = lane & 15;         // 0..15
            #pragma unroll
            for (int sj = 0; sj < 4; ++sj) {
                int j = sj * 32 + w * 4 + jo;        // hv row 0..127
                const float* src = hv + (size_t)(bb * NL + j) * NH;
                #pragma unroll
                for (int sk = 0; sk < 4; ++sk) {
                    int kf = sk * 16 + kf0;          // float4 col 0..63
                    float4 t4 = *(const float4*)&src[kf * 4];
                    v2_s[2 * kf + 0][j + 1] = make_float2(t4.x, t4.y);
                    v2_s[2 * kf + 1][j + 1] = make_float2(t4.z, t4.w);
                }
            }
            if (w == 0) {                            // vroot -> col 0
                float4 t4 = *(const float4*)&vroot[lane * 4];
                v2_s[2 * lane + 0][0] = make_float2(t4.x, t4.y);
                v2_s[2 * lane + 1][0] = make_float2(t4.z, t4.w);
            }
        }
        __syncthreads();                 // ONE barrier; compute is unbroken below

        float acc1 = 0.f, acc2 = 0.f, s128 = 0.f, lacc = 0.f;

        __builtin_amdgcn_s_setprio(1);
        #pragma unroll
        for (int c = 0; c < 4; ++c) {
            int k0 = c * 64;
            int kb = k0 >> 1;            // base kk2 for this chunk
            const float2* urow = u2_s[w] + kb;
            const float2* warow = wa2_s + kb;

            // ---- arc scores: lane covers j=lane and j=lane+64 ----
            #pragma unroll 8
            for (int kk2 = 0; kk2 < 32; ++kk2) {
                float2 u2 = urow[kk2];
                float2 w2 = warow[kk2];
                float2 va = v2_s[kb + kk2][lane];
                float2 vb = v2_s[kb + kk2][lane + 64];
                acc1 += fmaxf(u2.x + va.x, 0.f) * w2.x
                      + fmaxf(u2.y + va.y, 0.f) * w2.y;
                acc2 += fmaxf(u2.x + vb.x, 0.f) * w2.x
                      + fmaxf(u2.y + vb.y, 0.f) * w2.y;
            }
            // ---- j=128 partial + sel staging (lanes 0..31, kk2=lane) ----
            if (lane < 32) {
                float2 u2 = urow[lane];
                float2 w2 = warow[lane];
                float2 vv = v2_s[kb + lane][128];
                s128 += fmaxf(u2.x + vv.x, 0.f) * w2.x
                      + fmaxf(u2.y + vv.y, 0.f) * w2.y;
                float2 vs = v2_s[kb + lane][arc_s[w]];
                sel2_s[lane][w] = make_float2(fmaxf(u2.x + vs.x, 0.f),
                                              fmaxf(u2.y + vs.y, 0.f));
            }
            // ---- label logit partials: lane = tag, W_lab direct (L1) ----
            if (lane < NTAGS) {
                #pragma unroll 8
                for (int kk2 = 0; kk2 < 32; ++kk2) {
                    float2 s2 = sel2_s[kk2][w];
                    float w0 = W_lab[(size_t)(k0 + 2 * kk2) * NTAGS + lane];
                    float w1 = W_lab[(size_t)(k0 + 2 * kk2 + 1) * NTAGS + lane];
                    lacc = fmaf(s2.x, w0, fmaf(s2.y, w1, lacc));
                }
            }
        }
        __builtin_amdgcn_s_setprio(0);

        // ---- arc softmax CE (full-wave shuffles) ----
        float s128t = s128;
        #pragma unroll
        for (int off = 32; off > 0; off >>= 1)
            s128t += __shfl_xor(s128t, off);
        float m = fmaxf(acc1, acc2);
        #pragma unroll
        for (int off = 32; off > 0; off >>= 1)
            m = fmaxf(m, __shfl_xor(m, off));
        m = fmaxf(m, s128t);
        float e = expf(acc1 - m) + expf(acc2 - m);
        #pragma unroll
        for (int off = 32; off > 0; off >>= 1)
            e += __shfl_xor(e, off);
        e += expf(s128t - m);
        int a = arc_s[w];
        float cand = (a < 64) ? acc1 : acc2;
        float s_a = __shfl(cand, a & 63, 64);
        if (a == 128) s_a = s128t;
        float arc_ce = (m + logf(e)) - s_a;

        // ---- label softmax CE ----
        float logit = (lane < NTAGS) ? (lacc + b_lab[lane]) : -INFINITY;
        float m2 = logit;
        #pragma unroll
        for (int off = 32; off > 0; off >>= 1)
            m2 = fmaxf(m2, __shfl_xor(m2, off));
        float e2 = (lane < NTAGS) ? expf(logit - m2) : 0.f;
        #pragma unroll
        for (int off = 32; off > 0; off >>= 1)
            e2 += __shfl_xor(e2, off);
        float l_t = __shfl(logit, lab_s[w], 64);
        float lab_ce = (m2 + logf(e2)) - l_t;

        float tot = ((i0 + w) < slen) ? (arc_ce + lab_ce) : 0.f;
        if (lane == 0) ce_s[w] = tot;
        __syncthreads();
        if (tid == 0)
            atomicAdd(accum, ce_s[0] + ce_s[1] + ce_s[2] + ce_s[3]
                           + ce_s[4] + ce_s[5] + ce_s[6] + ce_s[7]);
    }

    // ---- done counter; last block finalizes ----
    if (tid == 0) {
        __threadfence();
        int prev = atomicAdd((int*)accum + 1, 1);
        if (prev == NBLK - 1) {
            int d = 0;
            #pragma unroll
            for (int q = 0; q < NB; ++q) d += slens[q];
            float s = atomicAdd(accum, 0.f);   // coherent read
            out[0] = 0.5f * s / fmaxf((float)d, 1.f);
        }
    }
}

extern "C" void kernel_launch(void* const* d_in, const int* in_sizes, int n_in,
                              void* d_out, int out_size, void* d_ws, size_t ws_size,
                              hipStream_t stream) {
    (void)in_sizes; (void)n_in; (void)out_size; (void)ws_size;
    const float* ctx   = (const float*)d_in[0];
    const int*   slens = (const int*)  d_in[1];
    const int*   arcs  = (const int*)  d_in[2];
    const int*   labs  = (const int*)  d_in[3];
    const float* W1    = (const float*)d_in[4];
    const float* b1    = (const float*)d_in[5];
    const float* root  = (const float*)d_in[6];
    const float* Wp    = (const float*)d_in[7];
    const float* bp    = (const float*)d_in[8];
    const float* W_arc = (const float*)d_in[9];
    // d_in[10] = b_arc: constant shift, cancels in arc log-softmax CE
    const float* W_lab = (const float*)d_in[11];
    const float* b_lab = (const float*)d_in[12];
    float* out = (float*)d_out;

    float* ws    = (float*)d_ws;
    float* h     = ws + H_OFF;
    float* u     = ws + U_OFF;
    float* hv    = ws + HV_OFF;
    float* vroot = ws + VROOT_OFF;
    float* accum = ws + ACC_OFF;

    gemm_hidden<<<dim3(64, 4, 2), 256, 0, stream>>>(ctx, W1, Wp, root, h, vroot, accum);
    gemm_uv<<<dim3(32, 16), 256, 0, stream>>>(h, b1, Wp, bp, u, hv);
    score_loss_kernel<<<dim3(NB, 16), 512, 0, stream>>>(
        u, hv, vroot, W_arc, W_lab, b_lab, slens, arcs, labs, accum, out);
}